// Round 1
// baseline (213.358 us; speedup 1.0000x reference)
//
#include <hip/hip_runtime.h>

// Round-8: HALO bricks. R7 was fetch-bound at the random-64B-line ceiling
// (dur 86us == FETCH 258MB / 3.1TB/s; VALU floor ~56us). Brick line stays
// 64B fp16 = 4x2x4 voxels (packing x[1:0]<<4 | y[0]<<3 | z[1:0]), but bricks
// are anchored on a 3x2x3 USEFUL grid: +1 halo in x and z (edge-clamped at
// retile). A 2x2x2 stencil then never crosses in x or z: lines/pt 2.34->1.5,
// and the conditional z-straddle load path vanishes (4 unconditional u64
// loads, both z taps inside one u64). Cost: bricks 32MB -> 60.6MB.
// Fallbacks: R7 32MB brick path if ws < 61MB; direct f32 gather if ws < 32MB.

#define NPTS (64 * 32 * 32 * 32)
#define NBLK (NPTS / 256)
#define SSTR 40   // shorts per LDS activation row (80 B)

// halo-brick geometry
#define BXN 86
#define BYN 128
#define BZN 86
#define NBRICK (BXN * BYN * BZN)        // 946,688 lines * 64B = 60.6 MB
#define RETILE_T (NBRICK * 8)           // 7,573,504 u64 writes
#define RETILE_BLK (RETILE_T / 256)     // 29,584 blocks (exact)

typedef __attribute__((ext_vector_type(8))) short bf16x8;
typedef __attribute__((ext_vector_type(4))) short s16x4;
typedef __attribute__((ext_vector_type(4))) float f32x4;
typedef unsigned long long u64;
typedef unsigned short u16;

__device__ __forceinline__ short bf16rne(float f) {
    unsigned u = __builtin_bit_cast(unsigned, f);
    return (short)((u + 0x7fffu + ((u >> 16) & 1u)) >> 16);
}
__device__ __forceinline__ float bf16tof(short s) {
    return __builtin_bit_cast(float, ((unsigned)(unsigned short)s) << 16);
}
__device__ __forceinline__ float h2f(u16 h) {
    return (float)__builtin_bit_cast(_Float16, h);
}
__device__ __forceinline__ u16 f2h(float f) {
    return __builtin_bit_cast(u16, (_Float16)f);
}

// ---- R7 retile: vol (256^3 f32) -> 32MB fp16 bricks, brick grid 64x128x64 ----
__global__ __launch_bounds__(256)
void retile_k(const float4* __restrict__ vol, u64* __restrict__ dst) {
    int t   = blockIdx.x * 256 + threadIdx.x;
    int q   = t & 7;
    int gz  = (t >> 3) & 63;
    int gyx = t >> 9;
    int x = ((gyx >> 7) << 2) + (q >> 1);
    int y = ((gyx & 127) << 1) + (q & 1);
    float4 v = vol[(((x << 8) + y) << 6) + gz];
    u64 r =  (u64)f2h(v.x)
          | ((u64)f2h(v.y) << 16)
          | ((u64)f2h(v.z) << 32)
          | ((u64)f2h(v.w) << 48);
    dst[t] = r;
}

// ---- R8 retile: vol -> halo bricks. Brick (bx,by,bz) holds voxels
// x = bx*3 + 0..3, y = by*2 + 0..1, z = bz*3 + 0..3, all clamped to <=255.
// dst u64 index = brick*8 + q, q = dx*2 + dy (dx = x within brick 0..3,
// dy = y within brick 0..1); the u64 holds the 4 z voxels.
// Writes fully coalesced; reads are overlapping z-runs from L2/L3-resident vol.
__global__ __launch_bounds__(256)
void retile_halo_k(const float* __restrict__ vol, u64* __restrict__ dst) {
    int t  = blockIdx.x * 256 + threadIdx.x;    // 0 .. RETILE_T-1
    int q  = t & 7;
    int b  = t >> 3;                            // brick id, bz fastest
    int bz = (int)((unsigned)b % 86u);
    int r  = (int)((unsigned)b / 86u);
    int by = r & 127;
    int bx = r >> 7;
    int x  = min(bx * 3 + (q >> 1), 255);
    int y  = (by << 1) + (q & 1);
    int z0 = bz * 3;
    const float* row = vol + (((x << 8) + y) << 8);
    float v0 = row[z0];
    float v1 = row[min(z0 + 1, 255)];
    float v2 = row[min(z0 + 2, 255)];
    float v3 = row[min(z0 + 3, 255)];
    u64 rr = (u64)f2h(v0)
          | ((u64)f2h(v1) << 16)
          | ((u64)f2h(v2) << 32)
          | ((u64)f2h(v3) << 48);
    dst[t] = rr;
}

// MODE: 0 = direct f32 gather, 1 = R7 32MB bricks, 2 = R8 halo bricks
template <int MODE>
__global__ __launch_bounds__(256, 8)
void deform_sample_k(const float4* __restrict__ x,    // (N,4)
                     const float4* __restrict__ W1,   // 3x32
                     const float4* __restrict__ b1,   // 32
                     const float*  __restrict__ W2,   // 32x32 [in][out]
                     const float*  __restrict__ b2,
                     const float*  __restrict__ W3,
                     const float*  __restrict__ b3,
                     const float*  __restrict__ Wf,   // 32x3
                     const float*  __restrict__ bf_,  // 3
                     const float*  __restrict__ volf, // 256^3 f32 (MODE 0)
                     const u64*    __restrict__ volh, // fp16 bricks (MODE 1/2)
                     float* __restrict__ out)
{
    __shared__ short lds[4 * 64 * SSTR];   // 20,480 B
    const int tid  = threadIdx.x;
    const int lane = tid & 63;
    const int wv   = tid >> 6;
    const int m16  = lane & 15;
    const int q    = lane >> 4;
    short* __restrict__ L = &lds[wv * 64 * SSTR];

    const int p = blockIdx.x * 256 + tid;   // grid exact: 8192 blocks

    const float4 xv = x[p];
    const float c0 = xv.x, c1 = xv.y, c2 = xv.z;

    // ---- layer 1 per-lane: h = cos(c@W1+b1), bf16 rows into LDS ----
    {
        bf16x8 hw;
        #pragma unroll
        for (int j4 = 0; j4 < 8; ++j4) {
            float4 wa = W1[j4], wb = W1[8 + j4], wc = W1[16 + j4], bb = b1[j4];
            float v0 = __cosf(fmaf(c0, wa.x, fmaf(c1, wb.x, fmaf(c2, wc.x, bb.x))));
            float v1 = __cosf(fmaf(c0, wa.y, fmaf(c1, wb.y, fmaf(c2, wc.y, bb.y))));
            float v2 = __cosf(fmaf(c0, wa.z, fmaf(c1, wb.z, fmaf(c2, wc.z, bb.z))));
            float v3 = __cosf(fmaf(c0, wa.w, fmaf(c1, wb.w, fmaf(c2, wc.w, bb.w))));
            int o = (j4 & 1) * 4;
            hw[o+0] = bf16rne(v0); hw[o+1] = bf16rne(v1);
            hw[o+2] = bf16rne(v2); hw[o+3] = bf16rne(v3);
            if (j4 & 1)
                *(bf16x8*)&L[lane * SSTR + (j4 - 1) * 4] = hw;
        }
    }
    __syncthreads();

    // ---- layers 2 and 3 via MFMA (A=weights, B=activations) ----
    const float* const Wly[2] = { W2, W3 };
    const float* const bly[2] = { b2, b3 };
    #pragma unroll
    for (int ly = 0; ly < 2; ++ly) {
        const float* __restrict__ W  = Wly[ly];
        const float* __restrict__ bb = bly[ly];
        bf16x8 A0, A1;
        #pragma unroll
        for (int j = 0; j < 8; ++j) {
            A0[j] = bf16rne(W[(q * 8 + j) * 32 + m16]);
            A1[j] = bf16rne(W[(q * 8 + j) * 32 + 16 + m16]);
        }
        const float4 blo = *(const float4*)&bb[q * 4];
        const float4 bhi = *(const float4*)&bb[16 + q * 4];

        #pragma unroll
        for (int t = 0; t < 4; ++t) {
            bf16x8 bfrag = *(const bf16x8*)&L[(t * 16 + m16) * SSTR + q * 8];
            f32x4 z = { 0.f, 0.f, 0.f, 0.f };
            f32x4 d0 = __builtin_amdgcn_mfma_f32_16x16x32_bf16(A0, bfrag, z, 0, 0, 0);
            f32x4 d1 = __builtin_amdgcn_mfma_f32_16x16x32_bf16(A1, bfrag, z, 0, 0, 0);

            s16x4 w0, w1;
            w0[0] = bf16rne(__cosf(d0[0] + blo.x));
            w0[1] = bf16rne(__cosf(d0[1] + blo.y));
            w0[2] = bf16rne(__cosf(d0[2] + blo.z));
            w0[3] = bf16rne(__cosf(d0[3] + blo.w));
            w1[0] = bf16rne(__cosf(d1[0] + bhi.x));
            w1[1] = bf16rne(__cosf(d1[1] + bhi.y));
            w1[2] = bf16rne(__cosf(d1[2] + bhi.z));
            w1[3] = bf16rne(__cosf(d1[3] + bhi.w));
            *(s16x4*)&L[(t * 16 + m16) * SSTR + q * 4]      = w0;
            *(s16x4*)&L[(t * 16 + m16) * SSTR + 16 + q * 4] = w1;
        }
        __syncthreads();
    }

    // ---- read own row; final c += 5*(h3@Wf + bf) ----
    float d0 = bf_[0], d1 = bf_[1], d2 = bf_[2];
    #pragma unroll
    for (int j4 = 0; j4 < 8; ++j4) {
        s16x4 v = *(const s16x4*)&L[lane * SSTR + j4 * 4];
        #pragma unroll
        for (int r = 0; r < 4; ++r) {
            float hv = bf16tof(v[r]);
            int ii = j4 * 4 + r;
            d0 = fmaf(hv, Wf[3*ii+0], d0);
            d1 = fmaf(hv, Wf[3*ii+1], d1);
            d2 = fmaf(hv, Wf[3*ii+2], d2);
        }
    }
    float e0 = fmaf(5.f, d0, c0);
    float e1 = fmaf(5.f, d1, c1);
    float e2 = fmaf(5.f, d2, c2);

    // ---- trilinear sample ----
    e0 = fminf(fmaxf(e0, 0.f), 255.f);
    e1 = fminf(fmaxf(e1, 0.f), 255.f);
    e2 = fminf(fmaxf(e2, 0.f), 255.f);
    float fl0 = floorf(e0), fl1 = floorf(e1), fl2 = floorf(e2);
    float fx = e0 - fl0, fy = e1 - fl1, fz = e2 - fl2;
    float gx = 1.f - fx, gy = 1.f - fy, gz = 1.f - fz;
    int x0 = (int)fl0, y0 = (int)fl1, z0 = (int)fl2;
    int x1 = min(x0 + 1, 255), y1 = min(y0 + 1, 255), z1 = min(z0 + 1, 255);

    float v000, v001, v010, v011, v100, v101, v110, v111;

    if constexpr (MODE == 2) {
        // halo bricks: x/z never cross a line; y crosses iff ly==1.
        // 4 unconditional u64 loads; both z taps inside each u64.
        int bx = (int)((unsigned)x0 / 3u);  int lx = x0 - bx * 3;
        int by = y0 >> 1;                   int ly = y0 & 1;
        int bz = (int)((unsigned)z0 / 3u);  int lz = z0 - bz * 3;
        const char* vb = (const char*)volh;
        const int lineA = ((((bx << 7) + by) * 86) + bz) << 6;
        const int byB   = min(by + 1, 127);
        const int lineB = (ly == 0) ? lineA
                                    : (((((bx << 7) + byB) * 86) + bz) << 6);
        // row-within-line for the y1 samples:
        //   ly==0 -> same line, y-row 1
        //   ly==1 -> next y-brick, y-row 0 (or row 1 = voxel 255 when y0==255)
        const int yrowB = (ly == 0) ? 1 : ((y0 == 255) ? 1 : 0);
        const int offA  = lx * 16 + ly * 8;
        const int offB  = lx * 16 + yrowB * 8;
        u64 LA0 = *(const u64*)(vb + lineA + offA);
        u64 LA1 = *(const u64*)(vb + lineA + offA + 16);
        u64 LB0 = *(const u64*)(vb + lineB + offB);
        u64 LB1 = *(const u64*)(vb + lineB + offB + 16);
        const int sh = lz * 16;
        u64 sA0 = LA0 >> sh, sA1 = LA1 >> sh, sB0 = LB0 >> sh, sB1 = LB1 >> sh;
        v000 = h2f((u16)sA0);  v001 = h2f((u16)(sA0 >> 16));
        v100 = h2f((u16)sA1);  v101 = h2f((u16)(sA1 >> 16));
        v010 = h2f((u16)sB0);  v011 = h2f((u16)(sB0 >> 16));
        v110 = h2f((u16)sB1);  v111 = h2f((u16)(sB1 >> 16));
    } else if constexpr (MODE == 1) {
        // byte addr = x[7:2]<<19 | y[7:1]<<12 | z[7:2]<<6 | x[1:0]<<4 | y[0]<<3
        const int lz  = z0 & 3;
        const int zp  = (z0 >> 2) << 6;
        const int xp0 = ((x0 >> 2) << 19) | ((x0 & 3) << 4);
        const int xp1 = ((x1 >> 2) << 19) | ((x1 & 3) << 4);
        const int yp0 = ((y0 >> 1) << 12) | ((y0 & 1) << 3);
        const int yp1 = ((y1 >> 1) << 12) | ((y1 & 1) << 3);
        const char* vb = (const char*)volh;
        const int a00 = xp0 | yp0 | zp, a10 = xp1 | yp0 | zp;
        const int a01 = xp0 | yp1 | zp, a11 = xp1 | yp1 | zp;
        u64 L00 = *(const u64*)(vb + a00);
        u64 L10 = *(const u64*)(vb + a10);
        u64 L01 = *(const u64*)(vb + a01);
        u64 L11 = *(const u64*)(vb + a11);
        u64 H00 = 0, H10 = 0, H01 = 0, H11 = 0;
        const bool crossz = (lz == 3) && (z0 < 255);
        if (crossz) {
            H00 = *(const u64*)(vb + a00 + 64);
            H10 = *(const u64*)(vb + a10 + 64);
            H01 = *(const u64*)(vb + a01 + 64);
            H11 = *(const u64*)(vb + a11 + 64);
        }
        const int sh = lz * 16;
        const bool in_line = (lz < 3);
        auto ext = [&](u64 lo, u64 hi, float& a, float& b) {
            u64 s = lo >> sh;
            a = h2f((u16)s);
            float b_in = h2f((u16)(s >> 16));
            float b_nx = h2f((u16)hi);
            b = in_line ? b_in : (crossz ? b_nx : a);
        };
        ext(L00, H00, v000, v001);
        ext(L10, H10, v100, v101);
        ext(L01, H01, v010, v011);
        ext(L11, H11, v110, v111);
    } else {
        int b00 = (x0 << 16) | (y0 << 8);
        int b01 = (x0 << 16) | (y1 << 8);
        int b10 = (x1 << 16) | (y0 << 8);
        int b11 = (x1 << 16) | (y1 << 8);
        v000 = volf[b00 + z0]; v001 = volf[b00 + z1];
        v010 = volf[b01 + z0]; v011 = volf[b01 + z1];
        v100 = volf[b10 + z0]; v101 = volf[b10 + z1];
        v110 = volf[b11 + z0]; v111 = volf[b11 + z1];
    }

    float r = gz * (gy * (gx*v000 + fx*v100) + fy * (gx*v010 + fx*v110))
            + fz * (gy * (gx*v001 + fx*v101) + fy * (gx*v011 + fx*v111));

    out[p] = r;
}

extern "C" void kernel_launch(void* const* d_in, const int* in_sizes, int n_in,
                              void* d_out, int out_size, void* d_ws, size_t ws_size,
                              hipStream_t stream) {
    const float4* x   = (const float4*)d_in[0];
    const float4* W1  = (const float4*)d_in[1];
    const float4* b1  = (const float4*)d_in[2];
    const float*  W2  = (const float*)d_in[3];
    const float*  b2  = (const float*)d_in[4];
    const float*  W3  = (const float*)d_in[5];
    const float*  b3  = (const float*)d_in[6];
    const float*  Wf  = (const float*)d_in[7];
    const float*  bf_ = (const float*)d_in[8];
    const float*  vol = (const float*)d_in[9];
    float* out = (float*)d_out;

    const size_t needH = (size_t)NBRICK * 64;      // 60.6 MB halo bricks
    const size_t need1 = (size_t)4194304 * 8;      // 32 MB R7 bricks
    if (ws_size >= needH) {
        u64* volh = (u64*)d_ws;
        retile_halo_k<<<RETILE_BLK, 256, 0, stream>>>(vol, volh);
        deform_sample_k<2><<<NBLK, 256, 0, stream>>>(x, W1, b1, W2, b2, W3, b3,
                                                     Wf, bf_, nullptr, volh, out);
    } else if (ws_size >= need1) {
        u64* volh = (u64*)d_ws;
        retile_k<<<16384, 256, 0, stream>>>((const float4*)vol, volh);
        deform_sample_k<1><<<NBLK, 256, 0, stream>>>(x, W1, b1, W2, b2, W3, b3,
                                                     Wf, bf_, nullptr, volh, out);
    } else {
        deform_sample_k<0><<<NBLK, 256, 0, stream>>>(x, W1, b1, W2, b2, W3, b3,
                                                     Wf, bf_, vol, nullptr, out);
    }
}